// Round 1
// baseline (137.475 us; speedup 1.0000x reference)
//
#include <hip/hip_runtime.h>
#include <hip/hip_bf16.h>

#define BATCH 8
#define SEQ   2048
#define DMS   1024
#define KSZ   128
#define OD    1152   // 1024 + 128

typedef unsigned short u16;
typedef unsigned int   u32;
typedef __attribute__((ext_vector_type(4))) float  f32x4;
typedef __attribute__((ext_vector_type(8))) __bf16 bf16x8;

union U128 { uint4 u4; bf16x8 b8; u16 us[8]; u32 u[4]; };

__device__ inline u16 f2bf(float f) {
  union { __bf16 h; u16 u; } c;
  c.h = (__bf16)f;
  return c.u;
}

__device__ inline float fexp2(float x) {
  float r;
  asm("v_exp_f32 %0, %1" : "=v"(r) : "v"(x));
  return r;
}

__device__ inline f32x4 mfma16(bf16x8 a, bf16x8 b, f32x4 c) {
  return __builtin_amdgcn_mfma_f32_16x16x32_bf16(a, b, c, 0, 0, 0);
}

// ---------------------------------------------------------------------------
// Kernel 1: fused K/V projection.
//   C[16384, 256] = X[16384,1024] @ [Wk | Wv] + [bk | bv]   (bf16 out)
//   - writes Kbf [B][S][128]      (row-major bf16; also serves as Q)
//   - writes Vt  [B][128][S]      (transposed bf16 so PV B-frags are contiguous)
//   - fuses out[:, 0:1024] = X passthrough into the A-tile loads
// Block: 512 thr (8 waves, 2x4), tile BM=64, BN=256, BK=64. Grid 256.
// ---------------------------------------------------------------------------
__global__ void __launch_bounds__(512) proj_kernel(
    const float* __restrict__ X, const float* __restrict__ Wk,
    const float* __restrict__ bk, const float* __restrict__ Wv,
    const float* __restrict__ bv, float* __restrict__ out,
    u16* __restrict__ Kbf, u16* __restrict__ Vt)
{
  __shared__ u16 Ab[64 * 64];    // A tile, bf16, XOR-swizzled rows
  __shared__ u16 Bt[256 * 64];   // B^T tile [n][k], bf16, swizzled; reused as C

  const int tid  = threadIdx.x;
  const int lane = tid & 63;
  const int wid  = tid >> 6;
  const int wm   = wid >> 2;       // 0..1
  const int wn   = wid & 3;        // 0..3
  const int l15  = lane & 15;
  const int g    = lane >> 4;
  const int m0   = blockIdx.x * 64;

  const int ar = tid >> 3;         // 0..63  A-stage row
  const int ac = (tid & 7) * 8;    // col base (8 f32 per thread)
  const int bn = tid & 255;        // 0..255 B-stage column n
  const int bh = tid >> 8;         // 0..1   k-half
  const float* bsrc = (bn < 128) ? (Wk + bn) : (Wv + (bn - 128));

  f32x4 acc[2][4];
#pragma unroll
  for (int i = 0; i < 2; ++i)
#pragma unroll
    for (int j = 0; j < 4; ++j) acc[i][j] = (f32x4){0.f, 0.f, 0.f, 0.f};

  char* AbB = (char*)Ab;
  char* BtB = (char*)Bt;

  for (int ks = 0; ks < 16; ++ks) {
    __syncthreads();
    // ---- stage A (64x64 f32 -> bf16) + passthrough write ----
    {
      const float* xp = X + (size_t)(m0 + ar) * DMS + ks * 64 + ac;
      float4 a0 = *(const float4*)xp;
      float4 a1 = *(const float4*)(xp + 4);
      float* op = out + (size_t)(m0 + ar) * OD + ks * 64 + ac;
      *(float4*)op = a0;
      *(float4*)(op + 4) = a1;
      U128 w;
      w.us[0] = f2bf(a0.x); w.us[1] = f2bf(a0.y);
      w.us[2] = f2bf(a0.z); w.us[3] = f2bf(a0.w);
      w.us[4] = f2bf(a1.x); w.us[5] = f2bf(a1.y);
      w.us[6] = f2bf(a1.z); w.us[7] = f2bf(a1.w);
      int ab = (ar * 128 + ac * 2) ^ ((ar & 7) << 4);
      *(uint4*)(AbB + ab) = w.u4;
    }
    // ---- stage B^T: thread owns column n, reads are row-coalesced per wave ----
    {
      const float* bp = bsrc + (size_t)(ks * 64 + bh * 32) * KSZ;
#pragma unroll
      for (int kc = 0; kc < 32; kc += 8) {
        U128 w;
#pragma unroll
        for (int j = 0; j < 8; ++j) w.us[j] = f2bf(bp[(size_t)(kc + j) * KSZ]);
        int bb = (bn * 128 + (bh * 32 + kc) * 2) ^ ((bn & 7) << 4);
        *(uint4*)(BtB + bb) = w.u4;
      }
    }
    __syncthreads();
    // ---- compute: 2 k-subtiles of 32 ----
#pragma unroll
    for (int kh = 0; kh < 2; ++kh) {
      bf16x8 af[2], bfr[4];
#pragma unroll
      for (int mf = 0; mf < 2; ++mf) {
        int m = wm * 32 + mf * 16 + l15;
        int ab = (m * 128 + (kh * 32 + g * 8) * 2) ^ ((m & 7) << 4);
        U128 u; u.u4 = *(uint4*)(AbB + ab); af[mf] = u.b8;
      }
#pragma unroll
      for (int nf = 0; nf < 4; ++nf) {
        int n = wn * 64 + nf * 16 + l15;
        int bb = (n * 128 + (kh * 32 + g * 8) * 2) ^ ((n & 7) << 4);
        U128 u; u.u4 = *(uint4*)(BtB + bb); bfr[nf] = u.b8;
      }
#pragma unroll
      for (int mf = 0; mf < 2; ++mf)
#pragma unroll
        for (int nf = 0; nf < 4; ++nf)
          acc[mf][nf] = mfma16(af[mf], bfr[nf], acc[mf][nf]);
    }
  }

  __syncthreads();   // all LDS reads done; reuse Bt as C[64][256]
#pragma unroll
  for (int nf = 0; nf < 4; ++nf) {
    int n = wn * 64 + nf * 16 + l15;
    float bias = (n < 128) ? bk[n] : bv[n - 128];
#pragma unroll
    for (int mf = 0; mf < 2; ++mf)
#pragma unroll
      for (int j = 0; j < 4; ++j) {
        int s = wm * 32 + mf * 16 + g * 4 + j;
        Bt[s * 256 + n] = f2bf(acc[mf][nf][j] + bias);
      }
  }
  __syncthreads();
  // ---- Kbf: coalesced row-major write ----
  {
    int r  = tid >> 3;
    int sg = tid & 7;
    const u16* src = Bt + r * 256 + sg * 16;
    uint4 v0 = *(const uint4*)src;
    uint4 v1 = *(const uint4*)(src + 8);
    u16* dst = Kbf + (size_t)(m0 + r) * KSZ + sg * 16;
    *(uint4*)dst = v0;
    *(uint4*)(dst + 8) = v1;
  }
  // ---- Vt: transpose V half out of LDS ----
  {
    int vc = tid & 127;
    int sh = tid >> 7;   // 0..3
    u32 pk[8];
#pragma unroll
    for (int j = 0; j < 8; ++j) {
      u32 lo = Bt[(sh * 16 + 2 * j) * 256 + 128 + vc];
      u32 hi = Bt[(sh * 16 + 2 * j + 1) * 256 + 128 + vc];
      pk[j] = lo | (hi << 16);
    }
    int bb   = m0 >> 11;             // batch index
    int sloc = (m0 & 2047) + sh * 16;
    u16* dst = Vt + ((size_t)bb * KSZ + vc) * SEQ + sloc;
    uint4 w0 = {pk[0], pk[1], pk[2], pk[3]};
    uint4 w1 = {pk[4], pk[5], pk[6], pk[7]};
    *(uint4*)dst = w0;
    *(uint4*)(dst + 8) = w1;
  }
}

// ---------------------------------------------------------------------------
// Kernel 2: causal flash attention, Q == K (shared projection).
//   Per wave: 16 q-rows; KV tiles of 32. Swapped QK^T (mfma(K,Q) -> S^T) so
//   the softmax reduction over t is 2 shfl_xor. P goes through a 1KB swizzled
//   per-wave LDS scratch to reach the PV A-operand layout. V read from Vt
//   (pre-transposed) so B-frags are contiguous dwordx4.
// Block: 128 thr (2 waves, 32 q-rows). Grid 512 = 64 q-tiles x 8 batches.
//   b = blockIdx&7  -> batch == XCD (round-robin dispatch) => K/V L2-resident.
//   qt = 63 - (blockIdx>>3): heavy (long-KV) blocks dispatch first.
// ---------------------------------------------------------------------------
__global__ void __launch_bounds__(128) attn_kernel(
    const u16* __restrict__ Kbf, const u16* __restrict__ Vt,
    float* __restrict__ out)
{
  __shared__ u16 Pl[2][16 * 32];
  const int tid  = threadIdx.x;
  const int lane = tid & 63;
  const int w    = tid >> 6;
  const int l15  = lane & 15;
  const int g    = lane >> 4;

  const int b     = blockIdx.x & 7;
  const int qt    = 63 - (blockIdx.x >> 3);
  const int qbase = qt * 32 + w * 16;

  const u16* Kb = Kbf + (size_t)b * SEQ * KSZ;
  const u16* Vb = Vt + (size_t)b * KSZ * SEQ;

  bf16x8 qf[4];
  {
    const u16* qp = Kb + (size_t)(qbase + l15) * KSZ + g * 8;
#pragma unroll
    for (int kv = 0; kv < 4; ++kv) {
      U128 u; u.u4 = *(const uint4*)(qp + kv * 32); qf[kv] = u.b8;
    }
  }

  f32x4 o[8];
#pragma unroll
  for (int i = 0; i < 8; ++i) o[i] = (f32x4){0.f, 0.f, 0.f, 0.f};
  float mrun = -3.0e38f;
  float lsum = 0.f;

  const float SC  = 0.08838834764831845f;   // 1/sqrt(128)
  const float L2E = 1.44269504088896341f;

  const int ntiles = qbase / 32 + 1;
  char* pb = (char*)&Pl[w][0];

  for (int ti = 0; ti < ntiles; ++ti) {
    const int t0 = ti * 32;
    const u16* kp = Kb + (size_t)(t0 + l15) * KSZ + g * 8;
    f32x4 st0 = (f32x4){0.f, 0.f, 0.f, 0.f};
    f32x4 st1 = (f32x4){0.f, 0.f, 0.f, 0.f};
#pragma unroll
    for (int kv = 0; kv < 4; ++kv) {
      U128 u0; u0.u4 = *(const uint4*)(kp + kv * 32);
      st0 = mfma16(u0.b8, qf[kv], st0);
    }
#pragma unroll
    for (int kv = 0; kv < 4; ++kv) {
      U128 u1; u1.u4 = *(const uint4*)(kp + 16 * KSZ + kv * 32);
      st1 = mfma16(u1.b8, qf[kv], st1);
    }
    float sv[8];
#pragma unroll
    for (int j = 0; j < 4; ++j) { sv[j] = st0[j] * SC; sv[4 + j] = st1[j] * SC; }
    if (ti == ntiles - 1) {
      const int q = qbase + l15;
#pragma unroll
      for (int tt = 0; tt < 2; ++tt)
#pragma unroll
        for (int j = 0; j < 4; ++j) {
          int t = t0 + tt * 16 + g * 4 + j;
          if (t > q) sv[tt * 4 + j] = -3.0e38f;
        }
    }
    float mx = sv[0];
#pragma unroll
    for (int i = 1; i < 8; ++i) mx = fmaxf(mx, sv[i]);
    mx = fmaxf(mx, __shfl_xor(mx, 16));
    mx = fmaxf(mx, __shfl_xor(mx, 32));
    float mnew = fmaxf(mrun, mx);
    float al = fexp2((mrun - mnew) * L2E);
    float p[8];
    float ps = 0.f;
#pragma unroll
    for (int i = 0; i < 8; ++i) { p[i] = fexp2((sv[i] - mnew) * L2E); ps += p[i]; }
    ps += __shfl_xor(ps, 16);
    ps += __shfl_xor(ps, 32);
    lsum = lsum * al + ps;
    mrun = mnew;
    float alq[4];
#pragma unroll
    for (int j = 0; j < 4; ++j) alq[j] = __shfl(al, g * 4 + j);
#pragma unroll
    for (int nf = 0; nf < 8; ++nf)
#pragma unroll
      for (int j = 0; j < 4; ++j) o[nf][j] *= alq[j];
    // P (bf16) -> swizzled LDS, row q = l15
#pragma unroll
    for (int tt = 0; tt < 2; ++tt) {
      uint2 pw;
      pw.x = (u32)f2bf(p[tt * 4 + 0]) | ((u32)f2bf(p[tt * 4 + 1]) << 16);
      pw.y = (u32)f2bf(p[tt * 4 + 2]) | ((u32)f2bf(p[tt * 4 + 3]) << 16);
      int off = (l15 * 64 + tt * 32 + g * 8) ^ ((l15 & 6) << 3);
      *(uint2*)(pb + off) = pw;
    }
    bf16x8 pa;
    {
      int off = (l15 * 64 + g * 16) ^ ((l15 & 6) << 3);
      U128 u; u.u4 = *(uint4*)(pb + off);
      pa = u.b8;
    }
    const u16* vp = Vb + (size_t)l15 * SEQ + t0 + g * 8;
#pragma unroll
    for (int nf = 0; nf < 8; ++nf) {
      U128 u; u.u4 = *(const uint4*)(vp + (size_t)nf * 16 * SEQ);
      o[nf] = mfma16(pa, u.b8, o[nf]);
    }
  }
  float linv = 1.f / lsum;
  float lq[4];
#pragma unroll
  for (int j = 0; j < 4; ++j) lq[j] = __shfl(linv, g * 4 + j);
#pragma unroll
  for (int nf = 0; nf < 8; ++nf)
#pragma unroll
    for (int j = 0; j < 4; ++j)
      out[(size_t)(b * SEQ + qbase + g * 4 + j) * OD + 1024 + nf * 16 + l15] =
          o[nf][j] * lq[j];
}

extern "C" void kernel_launch(void* const* d_in, const int* in_sizes, int n_in,
                              void* d_out, int out_size, void* d_ws, size_t ws_size,
                              hipStream_t stream)
{
  const float* X  = (const float*)d_in[0];
  const float* Wk = (const float*)d_in[1];
  const float* bk = (const float*)d_in[2];
  const float* Wv = (const float*)d_in[3];
  const float* bv = (const float*)d_in[4];
  float* out = (float*)d_out;

  u16* Kbf = (u16*)d_ws;                                  // 4.19 MB
  u16* Vt  = Kbf + (size_t)BATCH * SEQ * KSZ;             // 4.19 MB

  proj_kernel<<<dim3(256), dim3(512), 0, stream>>>(X, Wk, bk, Wv, bv, out, Kbf, Vt);
  attn_kernel<<<dim3(512), dim3(128), 0, stream>>>(Kbf, Vt, out);
}

// Round 2
// 134.487 us; speedup vs baseline: 1.0222x; 1.0222x over previous
//
#include <hip/hip_runtime.h>
#include <hip/hip_bf16.h>

#define BATCH 8
#define SEQ   2048
#define DMS   1024
#define KSZ   128
#define OD    1152   // 1024 + 128

typedef unsigned short u16;
typedef unsigned int   u32;
typedef __attribute__((ext_vector_type(4))) float  f32x4;
typedef __attribute__((ext_vector_type(8))) __bf16 bf16x8;

union U128 { uint4 u4; bf16x8 b8; u16 us[8]; u32 u[4]; };

__device__ inline u16 f2bf(float f) {
  union { __bf16 h; u16 u; } c;
  c.h = (__bf16)f;
  return c.u;
}

__device__ inline float fexp2(float x) {
  float r;
  asm("v_exp_f32 %0, %1" : "=v"(r) : "v"(x));
  return r;
}

__device__ inline f32x4 mfma16(bf16x8 a, bf16x8 b, f32x4 c) {
  return __builtin_amdgcn_mfma_f32_16x16x32_bf16(a, b, c, 0, 0, 0);
}

// ---------------------------------------------------------------------------
// Kernel 0: prep — convert [Wk|Wv] (f32, k-major rows) into bf16 tiles laid
// out in the EXACT byte order proj's LDS wants (XOR-swizzle pre-applied), so
// proj stages B with pure global_load_lds (no VALU, no strided loads).
// Tile ks (32KB): u16 index = n*64 + (kk ^ ((n&7)<<3)), value W[ks*64+kk][n].
// ---------------------------------------------------------------------------
__global__ void __launch_bounds__(256) prep_kernel(
    const float* __restrict__ Wk, const float* __restrict__ Wv,
    u16* __restrict__ Wtiles)
{
  int T = blockIdx.x * 256 + threadIdx.x;   // 0..32767
  int n  = T & 255;
  int kc = (T >> 8) * 8;                    // 0..1016 step 8
  int ks = kc >> 6;
  int kk = kc & 63;
  const float* src = (n < 128) ? (Wk + n) : (Wv + (n - 128));
  U128 w;
#pragma unroll
  for (int j = 0; j < 8; ++j) w.us[j] = f2bf(src[(size_t)(kc + j) * KSZ]);
  u16* dst = Wtiles + ks * 16384 + n * 64 + (kk ^ ((n & 7) << 3));
  *(uint4*)dst = w.u4;
}

// ---------------------------------------------------------------------------
// Kernel 1: fused K/V projection.
//   C[16384, 256] = X[16384,1024] @ [Wk | Wv] + [bk | bv]   (bf16 out)
//   - writes Kbf [B][S][128], Vt [B][128][S] (transposed)
//   - fuses out[:, 0:1024] = X passthrough
//   B-stage = global_load_lds from pre-swizzled Wtiles.
// ---------------------------------------------------------------------------
__global__ void __launch_bounds__(512) proj_kernel(
    const float* __restrict__ X, const u16* __restrict__ Wtiles,
    const float* __restrict__ bk, const float* __restrict__ bv,
    float* __restrict__ out, u16* __restrict__ Kbf, u16* __restrict__ Vt)
{
  __shared__ u16 Ab[64 * 64];    // A tile, bf16, XOR-swizzled rows
  __shared__ u16 Bt[256 * 64];   // B^T tile [n][k], swizzled; reused as C

  const int tid  = threadIdx.x;
  const int lane = tid & 63;
  const int wid  = tid >> 6;
  const int wm   = wid >> 2;       // 0..1
  const int wn   = wid & 3;        // 0..3
  const int l15  = lane & 15;
  const int g    = lane >> 4;
  const int m0   = blockIdx.x * 64;

  const int ar = tid >> 3;         // 0..63  A-stage row
  const int ac = (tid & 7) * 8;    // col base (8 f32 per thread)

  f32x4 acc[2][4];
#pragma unroll
  for (int i = 0; i < 2; ++i)
#pragma unroll
    for (int j = 0; j < 4; ++j) acc[i][j] = (f32x4){0.f, 0.f, 0.f, 0.f};

  char* AbB = (char*)Ab;
  char* BtB = (char*)Bt;

  for (int ks = 0; ks < 16; ++ks) {
    __syncthreads();
    // ---- stage A (64x64 f32 -> bf16) + passthrough write ----
    {
      const float* xp = X + (size_t)(m0 + ar) * DMS + ks * 64 + ac;
      float4 a0 = *(const float4*)xp;
      float4 a1 = *(const float4*)(xp + 4);
      float* op = out + (size_t)(m0 + ar) * OD + ks * 64 + ac;
      *(float4*)op = a0;
      *(float4*)(op + 4) = a1;
      U128 w;
      w.us[0] = f2bf(a0.x); w.us[1] = f2bf(a0.y);
      w.us[2] = f2bf(a0.z); w.us[3] = f2bf(a0.w);
      w.us[4] = f2bf(a1.x); w.us[5] = f2bf(a1.y);
      w.us[6] = f2bf(a1.z); w.us[7] = f2bf(a1.w);
      int ab = (ar * 128 + ac * 2) ^ ((ar & 7) << 4);
      *(uint4*)(AbB + ab) = w.u4;
    }
    // ---- stage B^T: pure async copy of the pre-swizzled 32KB tile ----
    {
      const u16* wsrc = Wtiles + (size_t)ks * 16384 + wid * 2048 + lane * 8;
#pragma unroll
      for (int i = 0; i < 4; ++i) {
        __builtin_amdgcn_global_load_lds(
            (const __attribute__((address_space(1))) u32*)(wsrc + i * 512),
            (__attribute__((address_space(3))) u32*)(Bt + wid * 2048 + i * 512),
            16, 0, 0);
      }
    }
    __syncthreads();
    // ---- compute: 2 k-subtiles of 32 ----
#pragma unroll
    for (int kh = 0; kh < 2; ++kh) {
      bf16x8 af[2], bfr[4];
#pragma unroll
      for (int mf = 0; mf < 2; ++mf) {
        int m = wm * 32 + mf * 16 + l15;
        int ab = (m * 128 + (kh * 32 + g * 8) * 2) ^ ((m & 7) << 4);
        U128 u; u.u4 = *(uint4*)(AbB + ab); af[mf] = u.b8;
      }
#pragma unroll
      for (int nf = 0; nf < 4; ++nf) {
        int n = wn * 64 + nf * 16 + l15;
        int bb = (n * 128 + (kh * 32 + g * 8) * 2) ^ ((n & 7) << 4);
        U128 u; u.u4 = *(uint4*)(BtB + bb); bfr[nf] = u.b8;
      }
#pragma unroll
      for (int mf = 0; mf < 2; ++mf)
#pragma unroll
        for (int nf = 0; nf < 4; ++nf)
          acc[mf][nf] = mfma16(af[mf], bfr[nf], acc[mf][nf]);
    }
  }

  __syncthreads();   // all LDS reads done; reuse Bt as C[64][256]
#pragma unroll
  for (int nf = 0; nf < 4; ++nf) {
    int n = wn * 64 + nf * 16 + l15;
    float bias = (n < 128) ? bk[n] : bv[n - 128];
#pragma unroll
    for (int mf = 0; mf < 2; ++mf)
#pragma unroll
      for (int j = 0; j < 4; ++j) {
        int s = wm * 32 + mf * 16 + g * 4 + j;
        Bt[s * 256 + n] = f2bf(acc[mf][nf][j] + bias);
      }
  }
  __syncthreads();
  // ---- Kbf: coalesced row-major write ----
  {
    int r  = tid >> 3;
    int sg = tid & 7;
    const u16* src = Bt + r * 256 + sg * 16;
    uint4 v0 = *(const uint4*)src;
    uint4 v1 = *(const uint4*)(src + 8);
    u16* dst = Kbf + (size_t)(m0 + r) * KSZ + sg * 16;
    *(uint4*)dst = v0;
    *(uint4*)(dst + 8) = v1;
  }
  // ---- Vt: transpose V half out of LDS ----
  {
    int vc = tid & 127;
    int sh = tid >> 7;   // 0..3
    u32 pk[8];
#pragma unroll
    for (int j = 0; j < 8; ++j) {
      u32 lo = Bt[(sh * 16 + 2 * j) * 256 + 128 + vc];
      u32 hi = Bt[(sh * 16 + 2 * j + 1) * 256 + 128 + vc];
      pk[j] = lo | (hi << 16);
    }
    int bb   = m0 >> 11;             // batch index
    int sloc = (m0 & 2047) + sh * 16;
    u16* dst = Vt + ((size_t)bb * KSZ + vc) * SEQ + sloc;
    uint4 w0 = {pk[0], pk[1], pk[2], pk[3]};
    uint4 w1 = {pk[4], pk[5], pk[6], pk[7]};
    *(uint4*)dst = w0;
    *(uint4*)(dst + 8) = w1;
  }
}

// ---------------------------------------------------------------------------
// Kernel 2: causal flash attention, Q == K.
//   8 waves/block = 2 q-halves x 4 KV-slices. Wave (qh, s) handles 16 q-rows
//   and KV-tiles ti = s, s+4, ... (online softmax per wave). Partial (o,m,l)
//   merged through LDS at the end by waves 0/1. Defer-max (THR=8) skips the
//   O-rescale on non-diagonal tiles. Grid 512 = 64 q-tiles x 8 batches,
//   heavy-first, batch == XCD.
// ---------------------------------------------------------------------------
__global__ void __launch_bounds__(512) attn_kernel(
    const u16* __restrict__ Kbf, const u16* __restrict__ Vt,
    float* __restrict__ out)
{
  __shared__ float Om[8][16][128];   // 64KB partial O, col-swizzled by row
  __shared__ float Ml[8][2][16];     // per-wave per-row (m, l)
  __shared__ u16  Pl[8][512];        // per-wave P scratch (swizzled)

  const int tid  = threadIdx.x;
  const int lane = tid & 63;
  const int w    = tid >> 6;
  const int qh   = w & 1;
  const int slc  = w >> 1;
  const int l15  = lane & 15;
  const int g    = lane >> 4;

  const int b     = blockIdx.x & 7;
  const int qt    = 63 - (blockIdx.x >> 3);
  const int qbase = qt * 32 + qh * 16;

  const u16* Kb = Kbf + (size_t)b * SEQ * KSZ;
  const u16* Vb = Vt + (size_t)b * KSZ * SEQ;

  bf16x8 qf[4];
  {
    const u16* qp = Kb + (size_t)(qbase + l15) * KSZ + g * 8;
#pragma unroll
    for (int kv = 0; kv < 4; ++kv) {
      U128 u; u.u4 = *(const uint4*)(qp + kv * 32); qf[kv] = u.b8;
    }
  }

  f32x4 o[8];
#pragma unroll
  for (int i = 0; i < 8; ++i) o[i] = (f32x4){0.f, 0.f, 0.f, 0.f};
  float mrun = -3.0e38f;
  float lsum = 0.f;

  const float SC  = 0.08838834764831845f;   // 1/sqrt(128)
  const float L2E = 1.44269504088896341f;

  const int ntiles = qt + 1;
  char* pb = (char*)&Pl[w][0];

  for (int ti = slc; ti < ntiles; ti += 4) {
    const int t0 = ti * 32;
    const u16* kp = Kb + (size_t)(t0 + l15) * KSZ + g * 8;
    f32x4 st0 = (f32x4){0.f, 0.f, 0.f, 0.f};
    f32x4 st1 = (f32x4){0.f, 0.f, 0.f, 0.f};
#pragma unroll
    for (int kv = 0; kv < 4; ++kv) {
      U128 u0; u0.u4 = *(const uint4*)(kp + kv * 32);
      st0 = mfma16(u0.b8, qf[kv], st0);
    }
#pragma unroll
    for (int kv = 0; kv < 4; ++kv) {
      U128 u1; u1.u4 = *(const uint4*)(kp + 16 * KSZ + kv * 32);
      st1 = mfma16(u1.b8, qf[kv], st1);
    }
    float sv[8];
#pragma unroll
    for (int j = 0; j < 4; ++j) { sv[j] = st0[j] * SC; sv[4 + j] = st1[j] * SC; }
    if (ti == ntiles - 1) {          // diagonal tile (only its owner wave)
      const int q = qbase + l15;
#pragma unroll
      for (int tt = 0; tt < 2; ++tt)
#pragma unroll
        for (int j = 0; j < 4; ++j) {
          int t = t0 + tt * 16 + g * 4 + j;
          if (t > q) sv[tt * 4 + j] = -3.0e38f;
        }
    }
    float mx = sv[0];
#pragma unroll
    for (int i = 1; i < 8; ++i) mx = fmaxf(mx, sv[i]);
    mx = fmaxf(mx, __shfl_xor(mx, 16));
    mx = fmaxf(mx, __shfl_xor(mx, 32));   // per-row (l15) tile max

    float p[8];
    float ps = 0.f;
    if (__all(mx - mrun <= 8.0f)) {
      // defer-max: keep old m, P bounded by e^8 — skip O-rescale entirely
#pragma unroll
      for (int i = 0; i < 8; ++i) { p[i] = fexp2((sv[i] - mrun) * L2E); ps += p[i]; }
      ps += __shfl_xor(ps, 16);
      ps += __shfl_xor(ps, 32);
      lsum += ps;
    } else {
      float mnew = fmaxf(mrun, mx);
      float al = fexp2((mrun - mnew) * L2E);
#pragma unroll
      for (int i = 0; i < 8; ++i) { p[i] = fexp2((sv[i] - mnew) * L2E); ps += p[i]; }
      ps += __shfl_xor(ps, 16);
      ps += __shfl_xor(ps, 32);
      lsum = lsum * al + ps;
      mrun = mnew;
      float alq[4];
#pragma unroll
      for (int j = 0; j < 4; ++j) alq[j] = __shfl(al, g * 4 + j);
#pragma unroll
      for (int nf = 0; nf < 8; ++nf)
#pragma unroll
        for (int j = 0; j < 4; ++j) o[nf][j] *= alq[j];
    }
    // P (bf16) -> swizzled LDS, row q = l15
#pragma unroll
    for (int tt = 0; tt < 2; ++tt) {
      uint2 pw;
      pw.x = (u32)f2bf(p[tt * 4 + 0]) | ((u32)f2bf(p[tt * 4 + 1]) << 16);
      pw.y = (u32)f2bf(p[tt * 4 + 2]) | ((u32)f2bf(p[tt * 4 + 3]) << 16);
      int off = (l15 * 64 + tt * 32 + g * 8) ^ ((l15 & 6) << 3);
      *(uint2*)(pb + off) = pw;
    }
    bf16x8 pa;
    {
      int off = (l15 * 64 + g * 16) ^ ((l15 & 6) << 3);
      U128 u; u.u4 = *(uint4*)(pb + off);
      pa = u.b8;
    }
    const u16* vp = Vb + (size_t)l15 * SEQ + t0 + g * 8;
#pragma unroll
    for (int nf = 0; nf < 8; ++nf) {
      U128 u; u.u4 = *(const uint4*)(vp + (size_t)nf * 16 * SEQ);
      o[nf] = mfma16(pa, u.b8, o[nf]);
    }
  }

  // ---- publish partials ----
#pragma unroll
  for (int nf = 0; nf < 8; ++nf)
#pragma unroll
    for (int j = 0; j < 4; ++j)
      Om[w][g * 4 + j][(nf * 16 + l15) ^ (g << 4)] = o[nf][j];
  if (g == 0) {
    Ml[w][0][l15] = mrun;
    Ml[w][1][l15] = lsum;
  }
  __syncthreads();

  // ---- merge 4 slices per q-half (waves 0 and 1) ----
  if (w < 2) {
    const int mqh = w;
#pragma unroll 1
    for (int r = 0; r < 16; ++r) {
      float m0 = Ml[0 + mqh][0][r], m1 = Ml[2 + mqh][0][r];
      float m2 = Ml[4 + mqh][0][r], m3 = Ml[6 + mqh][0][r];
      float M = fmaxf(fmaxf(m0, m1), fmaxf(m2, m3));
      float w0 = fexp2((m0 - M) * L2E), w1 = fexp2((m1 - M) * L2E);
      float w2 = fexp2((m2 - M) * L2E), w3 = fexp2((m3 - M) * L2E);
      float L = Ml[0 + mqh][1][r] * w0 + Ml[2 + mqh][1][r] * w1 +
                Ml[4 + mqh][1][r] * w2 + Ml[6 + mqh][1][r] * w3;
      int c = (2 * lane) ^ ((r & 12) << 2);
      float2 a0 = *(float2*)&Om[0 + mqh][r][c];
      float2 a1 = *(float2*)&Om[2 + mqh][r][c];
      float2 a2 = *(float2*)&Om[4 + mqh][r][c];
      float2 a3 = *(float2*)&Om[6 + mqh][r][c];
      float inv = 1.f / L;
      float rx = (a0.x * w0 + a1.x * w1 + a2.x * w2 + a3.x * w3) * inv;
      float ry = (a0.y * w0 + a1.y * w1 + a2.y * w2 + a3.y * w3) * inv;
      float2 res = {rx, ry};
      *(float2*)&out[(size_t)(b * SEQ + qt * 32 + mqh * 16 + r) * OD + 1024 + 2 * lane] = res;
    }
  }
}

extern "C" void kernel_launch(void* const* d_in, const int* in_sizes, int n_in,
                              void* d_out, int out_size, void* d_ws, size_t ws_size,
                              hipStream_t stream)
{
  const float* X  = (const float*)d_in[0];
  const float* Wk = (const float*)d_in[1];
  const float* bk = (const float*)d_in[2];
  const float* Wv = (const float*)d_in[3];
  const float* bv = (const float*)d_in[4];
  float* out = (float*)d_out;

  u16* Kbf    = (u16*)d_ws;                                // 4.19 MB
  u16* Vt     = Kbf + (size_t)BATCH * SEQ * KSZ;           // 4.19 MB
  u16* Wtiles = Vt + (size_t)BATCH * SEQ * KSZ;            // 512 KB

  prep_kernel<<<dim3(128), dim3(256), 0, stream>>>(Wk, Wv, Wtiles);
  proj_kernel<<<dim3(256), dim3(512), 0, stream>>>(X, Wtiles, bk, bv, out, Kbf, Vt);
  attn_kernel<<<dim3(512), dim3(512), 0, stream>>>(Kbf, Vt, out);
}

// Round 3
// 89.468 us; speedup vs baseline: 1.5366x; 1.5032x over previous
//
#include <hip/hip_runtime.h>
#include <hip/hip_bf16.h>

#define BATCH 8
#define SEQ   2048
#define DMS   1024
#define KSZ   128
#define OD    1152   // 1024 + 128

typedef unsigned short u16;
typedef unsigned int   u32;
typedef __attribute__((ext_vector_type(4)))  float  f32x4;
typedef __attribute__((ext_vector_type(16))) float  f32x16;
typedef __attribute__((ext_vector_type(8)))  __bf16 bf16x8;

union U128 { uint4 u4; bf16x8 b8; u16 us[8]; u32 u[4]; };

__device__ inline u16 f2bf(float f) {
  union { __bf16 h; u16 u; } c;
  c.h = (__bf16)f;
  return c.u;
}

__device__ inline float fexp2(float x) {
  float r;
  asm("v_exp_f32 %0, %1" : "=v"(r) : "v"(x));
  return r;
}

__device__ inline f32x4 mfma16(bf16x8 a, bf16x8 b, f32x4 c) {
  return __builtin_amdgcn_mfma_f32_16x16x32_bf16(a, b, c, 0, 0, 0);
}
__device__ inline f32x16 mfma32(bf16x8 a, bf16x8 b, f32x16 c) {
  return __builtin_amdgcn_mfma_f32_32x32x16_bf16(a, b, c, 0, 0, 0);
}

// ---------------------------------------------------------------------------
// Kernel 0: prep — [Wk|Wv] f32 -> bf16 tiles in proj's exact LDS byte order.
// ---------------------------------------------------------------------------
__global__ void __launch_bounds__(256) prep_kernel(
    const float* __restrict__ Wk, const float* __restrict__ Wv,
    u16* __restrict__ Wtiles)
{
  int T = blockIdx.x * 256 + threadIdx.x;   // 0..32767
  int n  = T & 255;
  int kc = (T >> 8) * 8;                    // 0..1016 step 8
  int ks = kc >> 6;
  int kk = kc & 63;
  const float* src = (n < 128) ? (Wk + n) : (Wv + (n - 128));
  U128 w;
#pragma unroll
  for (int j = 0; j < 8; ++j) w.us[j] = f2bf(src[(size_t)(kc + j) * KSZ]);
  u16* dst = Wtiles + ks * 16384 + n * 64 + (kk ^ ((n & 7) << 3));
  *(uint4*)dst = w.u4;
}

// ---------------------------------------------------------------------------
// Kernel 1: fused K/V projection (unchanged from R1).
// ---------------------------------------------------------------------------
__global__ void __launch_bounds__(512) proj_kernel(
    const float* __restrict__ X, const u16* __restrict__ Wtiles,
    const float* __restrict__ bk, const float* __restrict__ bv,
    float* __restrict__ out, u16* __restrict__ Kbf, u16* __restrict__ Vt)
{
  __shared__ u16 Ab[64 * 64];
  __shared__ u16 Bt[256 * 64];

  const int tid  = threadIdx.x;
  const int lane = tid & 63;
  const int wid  = tid >> 6;
  const int wm   = wid >> 2;
  const int wn   = wid & 3;
  const int l15  = lane & 15;
  const int g    = lane >> 4;
  const int m0   = blockIdx.x * 64;

  const int ar = tid >> 3;
  const int ac = (tid & 7) * 8;

  f32x4 acc[2][4];
#pragma unroll
  for (int i = 0; i < 2; ++i)
#pragma unroll
    for (int j = 0; j < 4; ++j) acc[i][j] = (f32x4){0.f, 0.f, 0.f, 0.f};

  char* AbB = (char*)Ab;
  char* BtB = (char*)Bt;

  for (int ks = 0; ks < 16; ++ks) {
    __syncthreads();
    {
      const float* xp = X + (size_t)(m0 + ar) * DMS + ks * 64 + ac;
      float4 a0 = *(const float4*)xp;
      float4 a1 = *(const float4*)(xp + 4);
      float* op = out + (size_t)(m0 + ar) * OD + ks * 64 + ac;
      *(float4*)op = a0;
      *(float4*)(op + 4) = a1;
      U128 w;
      w.us[0] = f2bf(a0.x); w.us[1] = f2bf(a0.y);
      w.us[2] = f2bf(a0.z); w.us[3] = f2bf(a0.w);
      w.us[4] = f2bf(a1.x); w.us[5] = f2bf(a1.y);
      w.us[6] = f2bf(a1.z); w.us[7] = f2bf(a1.w);
      int ab = (ar * 128 + ac * 2) ^ ((ar & 7) << 4);
      *(uint4*)(AbB + ab) = w.u4;
    }
    {
      const u16* wsrc = Wtiles + (size_t)ks * 16384 + wid * 2048 + lane * 8;
#pragma unroll
      for (int i = 0; i < 4; ++i) {
        __builtin_amdgcn_global_load_lds(
            (const __attribute__((address_space(1))) u32*)(wsrc + i * 512),
            (__attribute__((address_space(3))) u32*)(Bt + wid * 2048 + i * 512),
            16, 0, 0);
      }
    }
    __syncthreads();
#pragma unroll
    for (int kh = 0; kh < 2; ++kh) {
      bf16x8 af[2], bfr[4];
#pragma unroll
      for (int mf = 0; mf < 2; ++mf) {
        int m = wm * 32 + mf * 16 + l15;
        int ab = (m * 128 + (kh * 32 + g * 8) * 2) ^ ((m & 7) << 4);
        U128 u; u.u4 = *(uint4*)(AbB + ab); af[mf] = u.b8;
      }
#pragma unroll
      for (int nf = 0; nf < 4; ++nf) {
        int n = wn * 64 + nf * 16 + l15;
        int bb = (n * 128 + (kh * 32 + g * 8) * 2) ^ ((n & 7) << 4);
        U128 u; u.u4 = *(uint4*)(BtB + bb); bfr[nf] = u.b8;
      }
#pragma unroll
      for (int mf = 0; mf < 2; ++mf)
#pragma unroll
        for (int nf = 0; nf < 4; ++nf)
          acc[mf][nf] = mfma16(af[mf], bfr[nf], acc[mf][nf]);
    }
  }

  __syncthreads();
#pragma unroll
  for (int nf = 0; nf < 4; ++nf) {
    int n = wn * 64 + nf * 16 + l15;
    float bias = (n < 128) ? bk[n] : bv[n - 128];
#pragma unroll
    for (int mf = 0; mf < 2; ++mf)
#pragma unroll
      for (int j = 0; j < 4; ++j) {
        int s = wm * 32 + mf * 16 + g * 4 + j;
        Bt[s * 256 + n] = f2bf(acc[mf][nf][j] + bias);
      }
  }
  __syncthreads();
  {
    int r  = tid >> 3;
    int sg = tid & 7;
    const u16* src = Bt + r * 256 + sg * 16;
    uint4 v0 = *(const uint4*)src;
    uint4 v1 = *(const uint4*)(src + 8);
    u16* dst = Kbf + (size_t)(m0 + r) * KSZ + sg * 16;
    *(uint4*)dst = v0;
    *(uint4*)(dst + 8) = v1;
  }
  {
    int vc = tid & 127;
    int sh = tid >> 7;
    u32 pk[8];
#pragma unroll
    for (int j = 0; j < 8; ++j) {
      u32 lo = Bt[(sh * 16 + 2 * j) * 256 + 128 + vc];
      u32 hv = Bt[(sh * 16 + 2 * j + 1) * 256 + 128 + vc];
      pk[j] = lo | (hv << 16);
    }
    int bb   = m0 >> 11;
    int sloc = (m0 & 2047) + sh * 16;
    u16* dst = Vt + ((size_t)bb * KSZ + vc) * SEQ + sloc;
    uint4 w0 = {pk[0], pk[1], pk[2], pk[3]};
    uint4 w1 = {pk[4], pk[5], pk[6], pk[7]};
    *(uint4*)dst = w0;
    *(uint4*)(dst + 8) = w1;
  }
}

// ---------------------------------------------------------------------------
// Kernel 2: causal flash attention, Q == K, 32x32 MFMA, in-register softmax.
//   Block = (b, qt): 4 waves, each wave = one KV slice (ti = w, w+4, ...),
//   all 32 q-rows. Swapped QK^T (mfma(K,Q)): lane holds S^T column q=lane&31,
//   16 t-values; row softmax = 15 fmax + one shfl_xor(32). P redistributed to
//   the PV B-frag layout with 8 packs + 8 shfl_xor(32) + 8 selects (no LDS).
//   K prefetched across iterations; V issued at loop top. Partials merged via
//   LDS. Grid: 512 blocks; blocks i and i+256 (same CU slot) get qt=63-n and
//   qt=n so per-CU work is constant; b = i&7 pins batch to XCD.
// ---------------------------------------------------------------------------
__global__ void __launch_bounds__(256, 2) attn_kernel(
    const u16* __restrict__ Kbf, const u16* __restrict__ Vt,
    float* __restrict__ out)
{
  __shared__ float Om[4][128][33];   // [slice][v][q] partial O^T
  __shared__ float Ml[4][2][32];     // [slice][m|l][q]
  __shared__ float Wm[4][32];        // merge weights
  __shared__ float Li[32];           // 1/L

  const int tid  = threadIdx.x;
  const int lane = tid & 63;
  const int w    = tid >> 6;         // KV slice 0..3
  const int l31  = lane & 31;
  const int hi   = lane >> 5;

  const int bi = blockIdx.x;
  const int b  = bi & 7;
  const int qt = (bi < 256) ? (63 - (bi >> 3)) : ((bi >> 3) - 32);
  const int q0 = qt * 32;

  const u16* Kb = Kbf + (size_t)b * SEQ * KSZ;
  const u16* Vb = Vt  + (size_t)b * KSZ * SEQ;

  // Q fragments: B-operand, col q = q0+l31, k = ks*16 + hi*8 + j
  bf16x8 qf[8];
  {
    const u16* qp = Kb + (size_t)(q0 + l31) * KSZ + hi * 8;
#pragma unroll
    for (int ks = 0; ks < 8; ++ks) {
      U128 u; u.u4 = *(const uint4*)(qp + ks * 16); qf[ks] = u.b8;
    }
  }

  f32x16 o[4];
#pragma unroll
  for (int vb2 = 0; vb2 < 4; ++vb2)
#pragma unroll
    for (int i = 0; i < 16; ++i) o[vb2][i] = 0.f;

  float mrun = -3.0e38f, lsum = 0.f;
  const float SC  = 0.08838834764831845f;   // 1/sqrt(128)
  const float L2E = 1.44269504088896341f;

  // prologue: K frags for first tile of this slice
  bf16x8 kf[8];
  {
    int ti0 = (w <= qt) ? w : 0;
    const u16* kp = Kb + (size_t)(ti0 * 32 + l31) * KSZ + hi * 8;
#pragma unroll
    for (int ks = 0; ks < 8; ++ks) {
      U128 u; u.u4 = *(const uint4*)(kp + ks * 16); kf[ks] = u.b8;
    }
  }

  for (int ti = w; ti <= qt; ti += 4) {
    const int t0 = ti * 32;
    // ---- V loads for this tile (issued early; consumed after softmax) ----
    bf16x8 vf[4][2];
    {
      const u16* vp = Vb + (size_t)l31 * SEQ + t0 + hi * 8;
#pragma unroll
      for (int vb2 = 0; vb2 < 4; ++vb2)
#pragma unroll
        for (int th = 0; th < 2; ++th) {
          U128 u; u.u4 = *(const uint4*)(vp + (size_t)vb2 * 32 * SEQ + th * 16);
          vf[vb2][th] = u.b8;
        }
    }
    // ---- QK^T: S^T[t][q], lane: col q=l31, rows t=(r&3)+8(r>>2)+4hi ----
    f32x16 s;
#pragma unroll
    for (int i = 0; i < 16; ++i) s[i] = 0.f;
#pragma unroll
    for (int ks = 0; ks < 8; ++ks) s = mfma32(kf[ks], qf[ks], s);
    // ---- prefetch next-tile K (old kf fully consumed) ----
    {
      int tin = (ti + 4 <= qt) ? ti + 4 : ti;
      const u16* kp = Kb + (size_t)(tin * 32 + l31) * KSZ + hi * 8;
#pragma unroll
      for (int ks = 0; ks < 8; ++ks) {
        U128 u; u.u4 = *(const uint4*)(kp + ks * 16); kf[ks] = u.b8;
      }
    }
    // ---- scale + causal mask (diagonal tile only) ----
    float sv[16];
#pragma unroll
    for (int r = 0; r < 16; ++r) sv[r] = s[r] * SC;
    if (ti == qt) {
#pragma unroll
      for (int r = 0; r < 16; ++r) {
        int toff = (r & 3) + 8 * (r >> 2) + 4 * hi;
        if (toff > l31) sv[r] = -3.0e38f;
      }
    }
    // ---- row max: 15 in-reg fmax + one cross-half exchange ----
    float mx = sv[0];
#pragma unroll
    for (int r = 1; r < 16; ++r) mx = fmaxf(mx, sv[r]);
    mx = fmaxf(mx, __shfl_xor(mx, 32));
    // ---- online softmax with defer-max (THR=8) ----
    float p[16];
    float ps = 0.f;
    if (__all(mx - mrun <= 8.0f)) {
#pragma unroll
      for (int r = 0; r < 16; ++r) { p[r] = fexp2((sv[r] - mrun) * L2E); ps += p[r]; }
      ps += __shfl_xor(ps, 32);
      lsum += ps;
    } else {
      float mnew = fmaxf(mrun, mx);
      float al = fexp2((mrun - mnew) * L2E);
#pragma unroll
      for (int r = 0; r < 16; ++r) { p[r] = fexp2((sv[r] - mnew) * L2E); ps += p[r]; }
      ps += __shfl_xor(ps, 32);
      lsum = lsum * al + ps;
      mrun = mnew;
#pragma unroll
      for (int vb2 = 0; vb2 < 4; ++vb2)
#pragma unroll
        for (int i = 0; i < 16; ++i) o[vb2][i] *= al;
    }
    // ---- P -> PV B-frags (t=0..15 and t=16..31), in-register ----
    u32 c01 = (u32)f2bf(p[0])  | ((u32)f2bf(p[1])  << 16);
    u32 c23 = (u32)f2bf(p[2])  | ((u32)f2bf(p[3])  << 16);
    u32 c45 = (u32)f2bf(p[4])  | ((u32)f2bf(p[5])  << 16);
    u32 c67 = (u32)f2bf(p[6])  | ((u32)f2bf(p[7])  << 16);
    u32 c89 = (u32)f2bf(p[8])  | ((u32)f2bf(p[9])  << 16);
    u32 cAB = (u32)f2bf(p[10]) | ((u32)f2bf(p[11]) << 16);
    u32 cCD = (u32)f2bf(p[12]) | ((u32)f2bf(p[13]) << 16);
    u32 cEF = (u32)f2bf(p[14]) | ((u32)f2bf(p[15]) << 16);
    u32 d01 = __shfl_xor(c01, 32);
    u32 d23 = __shfl_xor(c23, 32);
    u32 d45 = __shfl_xor(c45, 32);
    u32 d67 = __shfl_xor(c67, 32);
    u32 d89 = __shfl_xor(c89, 32);
    u32 dAB = __shfl_xor(cAB, 32);
    u32 dCD = __shfl_xor(cCD, 32);
    u32 dEF = __shfl_xor(cEF, 32);
    U128 pf1, pf2;
    pf1.u[0] = hi ? d45 : c01;
    pf1.u[1] = hi ? d67 : c23;
    pf1.u[2] = hi ? c45 : d01;
    pf1.u[3] = hi ? c67 : d23;
    pf2.u[0] = hi ? dCD : c89;
    pf2.u[1] = hi ? dEF : cAB;
    pf2.u[2] = hi ? cCD : d89;
    pf2.u[3] = hi ? cEF : dAB;
    // ---- PV: O^T[v][q] += V^T-frag x P-frag ----
#pragma unroll
    for (int vb2 = 0; vb2 < 4; ++vb2) {
      o[vb2] = mfma32(vf[vb2][0], pf1.b8, o[vb2]);
      o[vb2] = mfma32(vf[vb2][1], pf2.b8, o[vb2]);
    }
  }

  // ---- publish partials ----
#pragma unroll
  for (int vb2 = 0; vb2 < 4; ++vb2)
#pragma unroll
    for (int r = 0; r < 16; ++r) {
      int v = vb2 * 32 + (r & 3) + 8 * (r >> 2) + 4 * hi;
      Om[w][v][l31] = o[vb2][r];
    }
  if (lane < 32) {
    Ml[w][0][l31] = mrun;
    Ml[w][1][l31] = lsum;
  }
  __syncthreads();

  // ---- merge weights (one lane per q-row) ----
  if (tid < 32) {
    float m0 = Ml[0][0][tid], m1 = Ml[1][0][tid];
    float m2 = Ml[2][0][tid], m3 = Ml[3][0][tid];
    float M  = fmaxf(fmaxf(m0, m1), fmaxf(m2, m3));
    float w0 = fexp2((m0 - M) * L2E), w1 = fexp2((m1 - M) * L2E);
    float w2 = fexp2((m2 - M) * L2E), w3 = fexp2((m3 - M) * L2E);
    float L  = Ml[0][1][tid] * w0 + Ml[1][1][tid] * w1 +
               Ml[2][1][tid] * w2 + Ml[3][1][tid] * w3;
    Wm[0][tid] = w0; Wm[1][tid] = w1; Wm[2][tid] = w2; Wm[3][tid] = w3;
    Li[tid] = 1.f / L;
  }
  __syncthreads();

  // ---- weighted merge + coalesced output write ----
  {
    const int q = tid >> 3;
    const int vbase = (tid & 7) * 16;
    float wq0 = Wm[0][q], wq1 = Wm[1][q], wq2 = Wm[2][q], wq3 = Wm[3][q];
    float li = Li[q];
    float* orow = out + (size_t)(b * SEQ + q0 + q) * OD + 1024 + vbase;
#pragma unroll
    for (int i = 0; i < 16; i += 4) {
      float4 res;
      res.x = (Om[0][vbase + i + 0][q] * wq0 + Om[1][vbase + i + 0][q] * wq1 +
               Om[2][vbase + i + 0][q] * wq2 + Om[3][vbase + i + 0][q] * wq3) * li;
      res.y = (Om[0][vbase + i + 1][q] * wq0 + Om[1][vbase + i + 1][q] * wq1 +
               Om[2][vbase + i + 1][q] * wq2 + Om[3][vbase + i + 1][q] * wq3) * li;
      res.z = (Om[0][vbase + i + 2][q] * wq0 + Om[1][vbase + i + 2][q] * wq1 +
               Om[2][vbase + i + 2][q] * wq2 + Om[3][vbase + i + 2][q] * wq3) * li;
      res.w = (Om[0][vbase + i + 3][q] * wq0 + Om[1][vbase + i + 3][q] * wq1 +
               Om[2][vbase + i + 3][q] * wq2 + Om[3][vbase + i + 3][q] * wq3) * li;
      *(float4*)(orow + i) = res;
    }
  }
}

extern "C" void kernel_launch(void* const* d_in, const int* in_sizes, int n_in,
                              void* d_out, int out_size, void* d_ws, size_t ws_size,
                              hipStream_t stream)
{
  const float* X  = (const float*)d_in[0];
  const float* Wk = (const float*)d_in[1];
  const float* bk = (const float*)d_in[2];
  const float* Wv = (const float*)d_in[3];
  const float* bv = (const float*)d_in[4];
  float* out = (float*)d_out;

  u16* Kbf    = (u16*)d_ws;                                // 4.19 MB
  u16* Vt     = Kbf + (size_t)BATCH * SEQ * KSZ;           // 4.19 MB
  u16* Wtiles = Vt + (size_t)BATCH * SEQ * KSZ;            // 512 KB

  prep_kernel<<<dim3(128), dim3(256), 0, stream>>>(Wk, Wv, Wtiles);
  proj_kernel<<<dim3(256), dim3(512), 0, stream>>>(X, Wtiles, bk, bv, out, Kbf, Vt);
  attn_kernel<<<dim3(512), dim3(256), 0, stream>>>(Kbf, Vt, out);
}

// Round 4
// 67.358 us; speedup vs baseline: 2.0410x; 1.3282x over previous
//
#include <hip/hip_runtime.h>
#include <hip/hip_bf16.h>

#define BATCH 8
#define SEQ   2048
#define DMS   1024
#define KSZ   128
#define OD    1152   // 1024 + 128

typedef unsigned short u16;
typedef unsigned int   u32;
typedef __attribute__((ext_vector_type(4)))  float  f32x4;
typedef __attribute__((ext_vector_type(16))) float  f32x16;
typedef __attribute__((ext_vector_type(8)))  __bf16 bf16x8;

union U128 { uint4 u4; bf16x8 b8; u16 us[8]; u32 u[4]; };

__device__ inline u16 f2bf(float f) {
  union { __bf16 h; u16 u; } c;
  c.h = (__bf16)f;
  return c.u;
}

__device__ inline float fexp2(float x) {
  float r;
  asm("v_exp_f32 %0, %1" : "=v"(r) : "v"(x));
  return r;
}

__device__ inline f32x4 mfma16(bf16x8 a, bf16x8 b, f32x4 c) {
  return __builtin_amdgcn_mfma_f32_16x16x32_bf16(a, b, c, 0, 0, 0);
}
__device__ inline f32x16 mfma32(bf16x8 a, bf16x8 b, f32x16 c) {
  return __builtin_amdgcn_mfma_f32_32x32x16_bf16(a, b, c, 0, 0, 0);
}

// Fragment-major layouts (per batch, stride 262144 u16 = 512 KB):
//   Kfrag[(t2*8+ks)*512 + hi*256 + l31*8 + j]          = K[t2*32+l31][ks*16+hi*8+j]
//   Vfrag[((t2*4+vb2)*2+th)*512 + hi*256 + l31*8 + j]  = V[t2*32+th*16+hi*8+j][vb2*32+l31]
// -> every attn frag load instruction covers a contiguous 1KB region.
#define BSTRIDE 262144

// ---------------------------------------------------------------------------
// Kernel 0: prep — [Wk|Wv] f32 -> bf16 tiles in proj's exact LDS byte order.
// ---------------------------------------------------------------------------
__global__ void __launch_bounds__(256) prep_kernel(
    const float* __restrict__ Wk, const float* __restrict__ Wv,
    u16* __restrict__ Wtiles)
{
  int T = blockIdx.x * 256 + threadIdx.x;   // 0..32767
  int n  = T & 255;
  int kc = (T >> 8) * 8;                    // 0..1016 step 8
  int ks = kc >> 6;
  int kk = kc & 63;
  const float* src = (n < 128) ? (Wk + n) : (Wv + (n - 128));
  U128 w;
#pragma unroll
  for (int j = 0; j < 8; ++j) w.us[j] = f2bf(src[(size_t)(kc + j) * KSZ]);
  u16* dst = Wtiles + ks * 16384 + n * 64 + (kk ^ ((n & 7) << 3));
  *(uint4*)dst = w.u4;
}

// ---------------------------------------------------------------------------
// Kernel 1: fused K/V projection. BM=32, BN=256, BK=64; 256 thr (4 waves),
// grid 512 => 2 independent blocks/CU (barrier-drain overlap).
// Epilogue writes Kfrag/Vfrag in MFMA-fragment-major order via a column-
// XOR-swizzled LDS C tile. Fuses out[:, :1024] = X passthrough.
// ---------------------------------------------------------------------------
__global__ void __launch_bounds__(256, 2) proj_kernel(
    const float* __restrict__ X, const u16* __restrict__ Wtiles,
    const float* __restrict__ bk, const float* __restrict__ bv,
    float* __restrict__ out, u16* __restrict__ Kfrag, u16* __restrict__ Vfrag)
{
  __shared__ u16 Ab[32 * 64];    // A tile bf16, XOR-swizzled rows (4KB)
  __shared__ u16 Bt[256 * 64];   // B^T tile [n][k] swizzled (32KB); reused as C

  const int tid  = threadIdx.x;
  const int lane = tid & 63;
  const int wid  = tid >> 6;       // 0..3 = wn
  const int l15  = lane & 15;
  const int g    = lane >> 4;
  const int m0   = blockIdx.x * 32;

  const int ar = tid >> 3;         // 0..31  A-stage row
  const int ac = (tid & 7) * 8;    // col base (8 f32)

  f32x4 acc[2][4];
#pragma unroll
  for (int i = 0; i < 2; ++i)
#pragma unroll
    for (int j = 0; j < 4; ++j) acc[i][j] = (f32x4){0.f, 0.f, 0.f, 0.f};

  char* AbB = (char*)Ab;
  char* BtB = (char*)Bt;

  for (int ks = 0; ks < 16; ++ks) {
    __syncthreads();
    // ---- stage A (32x64 f32 -> bf16) + passthrough ----
    {
      const float* xp = X + (size_t)(m0 + ar) * DMS + ks * 64 + ac;
      float4 a0 = *(const float4*)xp;
      float4 a1 = *(const float4*)(xp + 4);
      float* op = out + (size_t)(m0 + ar) * OD + ks * 64 + ac;
      *(float4*)op = a0;
      *(float4*)(op + 4) = a1;
      U128 w;
      w.us[0] = f2bf(a0.x); w.us[1] = f2bf(a0.y);
      w.us[2] = f2bf(a0.z); w.us[3] = f2bf(a0.w);
      w.us[4] = f2bf(a1.x); w.us[5] = f2bf(a1.y);
      w.us[6] = f2bf(a1.z); w.us[7] = f2bf(a1.w);
      int ab = (ar * 128 + ac * 2) ^ ((ar & 7) << 4);
      *(uint4*)(AbB + ab) = w.u4;
    }
    // ---- stage B^T: pure async copy of pre-swizzled 32KB tile ----
    {
      const u16* wsrc = Wtiles + (size_t)ks * 16384 + wid * 4096 + lane * 8;
#pragma unroll
      for (int i = 0; i < 8; ++i) {
        __builtin_amdgcn_global_load_lds(
            (const __attribute__((address_space(1))) u32*)(wsrc + i * 512),
            (__attribute__((address_space(3))) u32*)(Bt + wid * 4096 + i * 512),
            16, 0, 0);
      }
    }
    __syncthreads();
    // ---- compute ----
#pragma unroll
    for (int kh = 0; kh < 2; ++kh) {
      bf16x8 af[2], bfr[4];
#pragma unroll
      for (int mf = 0; mf < 2; ++mf) {
        int m = mf * 16 + l15;
        int ab = (m * 128 + (kh * 32 + g * 8) * 2) ^ ((m & 7) << 4);
        U128 u; u.u4 = *(uint4*)(AbB + ab); af[mf] = u.b8;
      }
#pragma unroll
      for (int nf = 0; nf < 4; ++nf) {
        int n = wid * 64 + nf * 16 + l15;
        int bb = (n * 128 + (kh * 32 + g * 8) * 2) ^ ((n & 7) << 4);
        U128 u; u.u4 = *(uint4*)(BtB + bb); bfr[nf] = u.b8;
      }
#pragma unroll
      for (int mf = 0; mf < 2; ++mf)
#pragma unroll
        for (int nf = 0; nf < 4; ++nf)
          acc[mf][nf] = mfma16(af[mf], bfr[nf], acc[mf][nf]);
    }
  }

  __syncthreads();   // LDS reads done; reuse Bt as C[32][256] (col-swizzled)
#pragma unroll
  for (int nf = 0; nf < 4; ++nf) {
    int n = wid * 64 + nf * 16 + l15;
    float bias = (n < 128) ? bk[n] : bv[n - 128];
#pragma unroll
    for (int mf = 0; mf < 2; ++mf)
#pragma unroll
      for (int j = 0; j < 4; ++j) {
        int s = mf * 16 + g * 4 + j;
        Bt[s * 256 + (n ^ ((s & 7) << 3))] = f2bf(acc[mf][nf][j] + bias);
      }
  }
  __syncthreads();

  const int bb   = m0 >> 11;            // batch
  const int tloc = (m0 & 2047) >> 5;    // tile within batch (BM==32)

  // ---- Kfrag store: frag-major, contiguous 128B runs per (ks) ----
  {
    int sl = tid >> 3;   // 0..31
    int ks = tid & 7;    // 0..7
    u16* dst = Kfrag + (size_t)bb * BSTRIDE + (size_t)(tloc * 8 + ks) * 512 + sl * 8;
#pragma unroll
    for (int hi2 = 0; hi2 < 2; ++hi2) {
      int n = ks * 16 + hi2 * 8;
      uint4 v = *(const uint4*)&Bt[sl * 256 + (n ^ ((sl & 7) << 3))];
      *(uint4*)(dst + hi2 * 256) = v;
    }
  }
  // ---- Vfrag store: transpose out of C (j runs along s) ----
  {
    int l31 = tid & 31;
    int vb2 = (tid >> 5) & 3;
    int th  = tid >> 7;   // 0..1
    int n   = 128 + vb2 * 32 + l31;
    u16* dst = Vfrag + (size_t)bb * BSTRIDE +
               (size_t)((tloc * 4 + vb2) * 2 + th) * 512 + l31 * 8;
#pragma unroll
    for (int hi = 0; hi < 2; ++hi) {
      U128 w;
#pragma unroll
      for (int j = 0; j < 8; ++j) {
        int s = th * 16 + hi * 8 + j;
        w.us[j] = Bt[s * 256 + (n ^ ((s & 7) << 3))];
      }
      *(uint4*)(dst + hi * 256) = w.u4;
    }
  }
}

// ---------------------------------------------------------------------------
// Kernel 2: causal flash attention, Q == K, 32x32 MFMA, in-register softmax.
//   4 waves/block = 4 KV slices over 32 q-rows; frag-major K/V loads are
//   contiguous 1KB per instruction. K prefetched across iterations; V issued
//   early. Defer-max THR=8. Partials merged via LDS. Grid 512: blocks i and
//   i+256 pair qt=63-n with qt=n (constant per-CU work); b=i&7 pins XCD.
// ---------------------------------------------------------------------------
__global__ void __launch_bounds__(256, 2) attn_kernel(
    const u16* __restrict__ Kfrag, const u16* __restrict__ Vfrag,
    float* __restrict__ out)
{
  __shared__ float Om[4][128][33];   // [slice][v][q] partial O^T
  __shared__ float Ml[4][2][32];     // [slice][m|l][q]
  __shared__ float Wm[4][32];        // merge weights
  __shared__ float Li[32];           // 1/L

  const int tid  = threadIdx.x;
  const int lane = tid & 63;
  const int w    = tid >> 6;         // KV slice 0..3
  const int l31  = lane & 31;
  const int hi   = lane >> 5;

  const int bi = blockIdx.x;
  const int b  = bi & 7;
  const int qt = (bi < 256) ? (63 - (bi >> 3)) : ((bi >> 3) - 32);
  const int q0 = qt * 32;

  const u16* Kb = Kfrag + (size_t)b * BSTRIDE;
  const u16* Vb = Vfrag + (size_t)b * BSTRIDE;
  const int loff = hi * 256 + l31 * 8;   // lane offset within a 512-u16 frag

  // Q fragments (Q == K): B-operand, col q=q0+l31, k=ks*16+hi*8+j
  bf16x8 qf[8];
  {
    const u16* qp = Kb + (size_t)(qt * 8) * 512 + loff;
#pragma unroll
    for (int ks = 0; ks < 8; ++ks) {
      U128 u; u.u4 = *(const uint4*)(qp + ks * 512); qf[ks] = u.b8;
    }
  }

  f32x16 o[4];
#pragma unroll
  for (int vb2 = 0; vb2 < 4; ++vb2)
#pragma unroll
    for (int i = 0; i < 16; ++i) o[vb2][i] = 0.f;

  float mrun = -3.0e38f, lsum = 0.f;
  const float SC  = 0.08838834764831845f;   // 1/sqrt(128)
  const float L2E = 1.44269504088896341f;

  // prologue: K frags for first tile of this slice
  bf16x8 kf[8];
  {
    int ti0 = (w <= qt) ? w : 0;
    const u16* kp = Kb + (size_t)(ti0 * 8) * 512 + loff;
#pragma unroll
    for (int ks = 0; ks < 8; ++ks) {
      U128 u; u.u4 = *(const uint4*)(kp + ks * 512); kf[ks] = u.b8;
    }
  }

  for (int ti = w; ti <= qt; ti += 4) {
    // ---- V loads (issued early; consumed after softmax) ----
    bf16x8 vf[4][2];
    {
      const u16* vp = Vb + (size_t)(ti * 8) * 512 + loff;
#pragma unroll
      for (int vb2 = 0; vb2 < 4; ++vb2)
#pragma unroll
        for (int th = 0; th < 2; ++th) {
          U128 u; u.u4 = *(const uint4*)(vp + (vb2 * 2 + th) * 512);
          vf[vb2][th] = u.b8;
        }
    }
    // ---- QK^T: S^T[t][q]; lane: col q=l31, rows t=(r&3)+8(r>>2)+4hi ----
    f32x16 s;
#pragma unroll
    for (int i = 0; i < 16; ++i) s[i] = 0.f;
#pragma unroll
    for (int ks = 0; ks < 8; ++ks) s = mfma32(kf[ks], qf[ks], s);
    // ---- prefetch next-tile K ----
    {
      int tin = (ti + 4 <= qt) ? ti + 4 : ti;
      const u16* kp = Kb + (size_t)(tin * 8) * 512 + loff;
#pragma unroll
      for (int ks = 0; ks < 8; ++ks) {
        U128 u; u.u4 = *(const uint4*)(kp + ks * 512); kf[ks] = u.b8;
      }
    }
    // ---- scale + causal mask (diagonal tile only) ----
    float sv[16];
#pragma unroll
    for (int r = 0; r < 16; ++r) sv[r] = s[r] * SC;
    if (ti == qt) {
#pragma unroll
      for (int r = 0; r < 16; ++r) {
        int toff = (r & 3) + 8 * (r >> 2) + 4 * hi;
        if (toff > l31) sv[r] = -3.0e38f;
      }
    }
    // ---- row max: 15 fmax + one cross-half exchange ----
    float mx = sv[0];
#pragma unroll
    for (int r = 1; r < 16; ++r) mx = fmaxf(mx, sv[r]);
    mx = fmaxf(mx, __shfl_xor(mx, 32));
    // ---- online softmax, defer-max THR=8 ----
    float p[16];
    float ps = 0.f;
    if (__all(mx - mrun <= 8.0f)) {
#pragma unroll
      for (int r = 0; r < 16; ++r) { p[r] = fexp2((sv[r] - mrun) * L2E); ps += p[r]; }
      ps += __shfl_xor(ps, 32);
      lsum += ps;
    } else {
      float mnew = fmaxf(mrun, mx);
      float al = fexp2((mrun - mnew) * L2E);
#pragma unroll
      for (int r = 0; r < 16; ++r) { p[r] = fexp2((sv[r] - mnew) * L2E); ps += p[r]; }
      ps += __shfl_xor(ps, 32);
      lsum = lsum * al + ps;
      mrun = mnew;
#pragma unroll
      for (int vb2 = 0; vb2 < 4; ++vb2)
#pragma unroll
        for (int i = 0; i < 16; ++i) o[vb2][i] *= al;
    }
    // ---- P -> PV B-frags, in-register (packs + shfl_xor(32) + selects) ----
    u32 c01 = (u32)f2bf(p[0])  | ((u32)f2bf(p[1])  << 16);
    u32 c23 = (u32)f2bf(p[2])  | ((u32)f2bf(p[3])  << 16);
    u32 c45 = (u32)f2bf(p[4])  | ((u32)f2bf(p[5])  << 16);
    u32 c67 = (u32)f2bf(p[6])  | ((u32)f2bf(p[7])  << 16);
    u32 c89 = (u32)f2bf(p[8])  | ((u32)f2bf(p[9])  << 16);
    u32 cAB = (u32)f2bf(p[10]) | ((u32)f2bf(p[11]) << 16);
    u32 cCD = (u32)f2bf(p[12]) | ((u32)f2bf(p[13]) << 16);
    u32 cEF = (u32)f2bf(p[14]) | ((u32)f2bf(p[15]) << 16);
    u32 d01 = __shfl_xor(c01, 32);
    u32 d23 = __shfl_xor(c23, 32);
    u32 d45 = __shfl_xor(c45, 32);
    u32 d67 = __shfl_xor(c67, 32);
    u32 d89 = __shfl_xor(c89, 32);
    u32 dAB = __shfl_xor(cAB, 32);
    u32 dCD = __shfl_xor(cCD, 32);
    u32 dEF = __shfl_xor(cEF, 32);
    U128 pf1, pf2;
    pf1.u[0] = hi ? d45 : c01;
    pf1.u[1] = hi ? d67 : c23;
    pf1.u[2] = hi ? c45 : d01;
    pf1.u[3] = hi ? c67 : d23;
    pf2.u[0] = hi ? dCD : c89;
    pf2.u[1] = hi ? dEF : cAB;
    pf2.u[2] = hi ? cCD : d89;
    pf2.u[3] = hi ? cEF : dAB;
    // ---- PV: O^T[v][q] += V^T-frag x P-frag ----
#pragma unroll
    for (int vb2 = 0; vb2 < 4; ++vb2) {
      o[vb2] = mfma32(vf[vb2][0], pf1.b8, o[vb2]);
      o[vb2] = mfma32(vf[vb2][1], pf2.b8, o[vb2]);
    }
  }

  // ---- publish partials ----
#pragma unroll
  for (int vb2 = 0; vb2 < 4; ++vb2)
#pragma unroll
    for (int r = 0; r < 16; ++r) {
      int v = vb2 * 32 + (r & 3) + 8 * (r >> 2) + 4 * hi;
      Om[w][v][l31] = o[vb2][r];
    }
  if (lane < 32) {
    Ml[w][0][l31] = mrun;
    Ml[w][1][l31] = lsum;
  }
  __syncthreads();

  // ---- merge weights (one lane per q-row) ----
  if (tid < 32) {
    float m0 = Ml[0][0][tid], m1 = Ml[1][0][tid];
    float m2 = Ml[2][0][tid], m3 = Ml[3][0][tid];
    float M  = fmaxf(fmaxf(m0, m1), fmaxf(m2, m3));
    float w0 = fexp2((m0 - M) * L2E), w1 = fexp2((m1 - M) * L2E);
    float w2 = fexp2((m2 - M) * L2E), w3 = fexp2((m3 - M) * L2E);
    float L  = Ml[0][1][tid] * w0 + Ml[1][1][tid] * w1 +
               Ml[2][1][tid] * w2 + Ml[3][1][tid] * w3;
    Wm[0][tid] = w0; Wm[1][tid] = w1; Wm[2][tid] = w2; Wm[3][tid] = w3;
    Li[tid] = 1.f / L;
  }
  __syncthreads();

  // ---- weighted merge + coalesced output write ----
  {
    const int q = tid >> 3;
    const int vbase = (tid & 7) * 16;
    float wq0 = Wm[0][q], wq1 = Wm[1][q], wq2 = Wm[2][q], wq3 = Wm[3][q];
    float li = Li[q];
    float* orow = out + (size_t)(b * SEQ + q0 + q) * OD + 1024 + vbase;
#pragma unroll
    for (int i = 0; i < 16; i += 4) {
      float4 res;
      res.x = (Om[0][vbase + i + 0][q] * wq0 + Om[1][vbase + i + 0][q] * wq1 +
               Om[2][vbase + i + 0][q] * wq2 + Om[3][vbase + i + 0][q] * wq3) * li;
      res.y = (Om[0][vbase + i + 1][q] * wq0 + Om[1][vbase + i + 1][q] * wq1 +
               Om[2][vbase + i + 1][q] * wq2 + Om[3][vbase + i + 1][q] * wq3) * li;
      res.z = (Om[0][vbase + i + 2][q] * wq0 + Om[1][vbase + i + 2][q] * wq1 +
               Om[2][vbase + i + 2][q] * wq2 + Om[3][vbase + i + 2][q] * wq3) * li;
      res.w = (Om[0][vbase + i + 3][q] * wq0 + Om[1][vbase + i + 3][q] * wq1 +
               Om[2][vbase + i + 3][q] * wq2 + Om[3][vbase + i + 3][q] * wq3) * li;
      *(float4*)(orow + i) = res;
    }
  }
}

extern "C" void kernel_launch(void* const* d_in, const int* in_sizes, int n_in,
                              void* d_out, int out_size, void* d_ws, size_t ws_size,
                              hipStream_t stream)
{
  const float* X  = (const float*)d_in[0];
  const float* Wk = (const float*)d_in[1];
  const float* bk = (const float*)d_in[2];
  const float* Wv = (const float*)d_in[3];
  const float* bv = (const float*)d_in[4];
  float* out = (float*)d_out;

  u16* Kfrag  = (u16*)d_ws;                                // 4 MB
  u16* Vfrag  = Kfrag + (size_t)BATCH * BSTRIDE;           // 4 MB
  u16* Wtiles = Vfrag + (size_t)BATCH * BSTRIDE;           // 512 KB

  prep_kernel<<<dim3(128), dim3(256), 0, stream>>>(Wk, Wv, Wtiles);
  proj_kernel<<<dim3(512), dim3(256), 0, stream>>>(X, Wtiles, bk, bv, out, Kfrag, Vfrag);
  attn_kernel<<<dim3(512), dim3(256), 0, stream>>>(Kfrag, Vfrag, out);
}

// Round 6
// 67.165 us; speedup vs baseline: 2.0468x; 1.0029x over previous
//
#include <hip/hip_runtime.h>
#include <hip/hip_bf16.h>

#define BATCH 8
#define SEQ   2048
#define DMS   1024
#define KSZ   128
#define OD    1152   // 1024 + 128

typedef unsigned short u16;
typedef unsigned int   u32;
typedef __attribute__((ext_vector_type(4)))  float  f32x4;
typedef __attribute__((ext_vector_type(16))) float  f32x16;
typedef __attribute__((ext_vector_type(8)))  __bf16 bf16x8;

union U128 { uint4 u4; bf16x8 b8; u16 us[8]; u32 u[4]; };

__device__ inline u16 f2bf(float f) {
  union { __bf16 h; u16 u; } c;
  c.h = (__bf16)f;
  return c.u;
}

__device__ inline float fexp2(float x) {
  float r;
  asm("v_exp_f32 %0, %1" : "=v"(r) : "v"(x));
  return r;
}

__device__ inline f32x4 mfma16(bf16x8 a, bf16x8 b, f32x4 c) {
  return __builtin_amdgcn_mfma_f32_16x16x32_bf16(a, b, c, 0, 0, 0);
}
__device__ inline f32x16 mfma32(bf16x8 a, bf16x8 b, f32x16 c) {
  return __builtin_amdgcn_mfma_f32_32x32x16_bf16(a, b, c, 0, 0, 0);
}

__device__ inline uint4 pack8bf(float4 a, float4 b) {
  U128 w;
  w.us[0] = f2bf(a.x); w.us[1] = f2bf(a.y);
  w.us[2] = f2bf(a.z); w.us[3] = f2bf(a.w);
  w.us[4] = f2bf(b.x); w.us[5] = f2bf(b.y);
  w.us[6] = f2bf(b.z); w.us[7] = f2bf(b.w);
  return w.u4;
}

__device__ inline void glds16(const u16* src, u16* ldsDst) {
  __builtin_amdgcn_global_load_lds(
      (const __attribute__((address_space(1))) u32*)src,
      (__attribute__((address_space(3))) u32*)ldsDst, 16, 0, 0);
}

// Fragment-major layouts (per batch, stride 262144 u16 = 512 KB):
//   Kfrag[(t2*8+ks)*512 + hi*256 + l31*8 + j]          = K[t2*32+l31][ks*16+hi*8+j]
//   Vfrag[((t2*4+vb2)*2+th)*512 + hi*256 + l31*8 + j]  = V[t2*32+th*16+hi*8+j][vb2*32+l31]
#define BSTRIDE 262144

// ---------------------------------------------------------------------------
// Kernel 0: prep — [Wk|Wv] f32 -> bf16 tiles in proj's exact LDS byte order.
// ---------------------------------------------------------------------------
__global__ void __launch_bounds__(256) prep_kernel(
    const float* __restrict__ Wk, const float* __restrict__ Wv,
    u16* __restrict__ Wtiles)
{
  int T = blockIdx.x * 256 + threadIdx.x;   // 0..32767
  int n  = T & 255;
  int kc = (T >> 8) * 8;                    // 0..1016 step 8
  int ks = kc >> 6;
  int kk = kc & 63;
  const float* src = (n < 128) ? (Wk + n) : (Wv + (n - 128));
  U128 w;
#pragma unroll
  for (int j = 0; j < 8; ++j) w.us[j] = f2bf(src[(size_t)(kc + j) * KSZ]);
  u16* dst = Wtiles + ks * 16384 + n * 64 + (kk ^ ((n & 7) << 3));
  *(uint4*)dst = w.u4;
}

// ---------------------------------------------------------------------------
// Kernel 1: fused K/V projection — issue-ahead double buffering, plain
// __syncthreads (correct by construction; compiler inserts all waits).
// BM=64, BN=256, BK=64; 512 thr (8 waves, 2x4); grid 256 (1 block/CU).
// Per step k: store out(k); issue X(k+1)->regs + glds W(k+1)->Bt[nxt];
// compute(cur); cvt+ds_write Ab[nxt]; barrier. Prefetch has the whole step
// to fly; the barrier drain enforces exactly the needed completion.
// ---------------------------------------------------------------------------
__global__ void __launch_bounds__(512, 1) proj_kernel(
    const float* __restrict__ X, const u16* __restrict__ Wtiles,
    const float* __restrict__ bk, const float* __restrict__ bv,
    float* __restrict__ out, u16* __restrict__ Kfrag, u16* __restrict__ Vfrag)
{
  __shared__ u16 Ab[2][64 * 64];    // 2 x 8 KB, XOR-swizzled rows
  __shared__ u16 Bt[2][256 * 64];   // 2 x 32 KB, pre-swizzled via Wtiles

  const int tid  = threadIdx.x;
  const int lane = tid & 63;
  const int wv   = tid >> 6;        // 0..7
  const int wm   = wv >> 2;         // 0..1
  const int wn   = wv & 3;          // 0..3
  const int l15  = lane & 15;
  const int g    = lane >> 4;
  const int m0   = blockIdx.x * 64;

  const int ar = tid >> 3;          // 0..63  A-stage row
  const int ac = (tid & 7) * 8;     // col base (8 f32)

  const float* xrow = X + (size_t)(m0 + ar) * DMS + ac;
  float*       orow = out + (size_t)(m0 + ar) * OD + ac;
  const int   abOff = (ar * 128 + ac * 2) ^ ((ar & 7) << 4);

  char* AbB = (char*)&Ab[0][0];
  char* BtB = (char*)&Bt[0][0];

  f32x4 acc[2][4];
#pragma unroll
  for (int i = 0; i < 2; ++i)
#pragma unroll
    for (int j = 0; j < 4; ++j) acc[i][j] = (f32x4){0.f, 0.f, 0.f, 0.f};

  float4 xv[2][2];

  // ---- prologue: X(0) -> regs -> Ab[0]; W(0) -> Bt[0] ----
  xv[0][0] = *(const float4*)(xrow);
  xv[0][1] = *(const float4*)(xrow + 4);
  {
    const u16* ws = Wtiles + wv * 512 + lane * 8;
    u16* wd = &Bt[0][0] + wv * 512;
#pragma unroll
    for (int r = 0; r < 4; ++r) glds16(ws + r * 4096, wd + r * 4096);
  }
  *(uint4*)(AbB + abOff) = pack8bf(xv[0][0], xv[0][1]);
  __syncthreads();

#pragma unroll
  for (int k = 0; k < 16; ++k) {
    const int cur = k & 1, nxt = cur ^ 1;
    // out passthrough for step k (fire-and-forget)
    *(float4*)(orow + k * 64)     = xv[cur][0];
    *(float4*)(orow + k * 64 + 4) = xv[cur][1];
    // issue-ahead prefetch of step k+1
    if (k < 15) {
      xv[nxt][0] = *(const float4*)(xrow + (k + 1) * 64);
      xv[nxt][1] = *(const float4*)(xrow + (k + 1) * 64 + 4);
      const u16* ws = Wtiles + (size_t)(k + 1) * 16384 + wv * 512 + lane * 8;
      u16* wd = &Bt[nxt][0] + wv * 512;
#pragma unroll
      for (int r = 0; r < 4; ++r) glds16(ws + r * 4096, wd + r * 4096);
    }
    // compute step k from buffer cur
#pragma unroll
    for (int kh = 0; kh < 2; ++kh) {
      bf16x8 af[2], bfr[4];
#pragma unroll
      for (int mf = 0; mf < 2; ++mf) {
        int m = wm * 32 + mf * 16 + l15;
        int ab = cur * 8192 + ((m * 128 + (kh * 32 + g * 8) * 2) ^ ((m & 7) << 4));
        U128 u; u.u4 = *(uint4*)(AbB + ab); af[mf] = u.b8;
      }
#pragma unroll
      for (int nf = 0; nf < 4; ++nf) {
        int n = wn * 64 + nf * 16 + l15;
        int bb = cur * 32768 + ((n * 128 + (kh * 32 + g * 8) * 2) ^ ((n & 7) << 4));
        U128 u; u.u4 = *(uint4*)(BtB + bb); bfr[nf] = u.b8;
      }
#pragma unroll
      for (int mf = 0; mf < 2; ++mf)
#pragma unroll
        for (int nf = 0; nf < 4; ++nf)
          acc[mf][nf] = mfma16(af[mf], bfr[nf], acc[mf][nf]);
    }
    // stage X(k+1) into Ab[nxt] (compiler waits on the load regs here)
    if (k < 15)
      *(uint4*)(AbB + nxt * 8192 + abOff) = pack8bf(xv[nxt][0], xv[nxt][1]);
    __syncthreads();
  }

  // ---- epilogue: C -> Bt[0] (col-swizzled) -> frag-major stores ----
  u16* Ct = &Bt[0][0];   // 64 x 256 u16 = 32 KB, fits buffer 0 exactly
#pragma unroll
  for (int nf = 0; nf < 4; ++nf) {
    int n = wn * 64 + nf * 16 + l15;
    float bias = (n < 128) ? bk[n] : bv[n - 128];
#pragma unroll
    for (int mf = 0; mf < 2; ++mf)
#pragma unroll
      for (int j = 0; j < 4; ++j) {
        int s = wm * 32 + mf * 16 + g * 4 + j;
        Ct[s * 256 + (n ^ ((s & 7) << 3))] = f2bf(acc[mf][nf][j] + bias);
      }
  }
  __syncthreads();

  const int bb    = m0 >> 11;            // batch
  const int tloc2 = (m0 & 2047) >> 5;    // first 32-row tile within batch

  // ---- Kfrag store: frag-major, contiguous runs ----
  {
    int sl = tid >> 3;   // 0..63 row within block
    int ks = tid & 7;    // 0..7
    int t2 = tloc2 + (sl >> 5);
    int lrow = sl & 31;
    u16* dst = Kfrag + (size_t)bb * BSTRIDE + (size_t)(t2 * 8 + ks) * 512 + lrow * 8;
#pragma unroll
    for (int hi2 = 0; hi2 < 2; ++hi2) {
      int n = ks * 16 + hi2 * 8;
      uint4 v = *(const uint4*)&Ct[sl * 256 + (n ^ ((sl & 7) << 3))];
      *(uint4*)(dst + hi2 * 256) = v;
    }
  }
  // ---- Vfrag store: transpose out of C ----
  {
    int l31 = tid & 31;
    int vb2 = (tid >> 5) & 3;
    int thh = (tid >> 7) & 1;
    int sh2 = tid >> 8;            // 0..1 (row-half of the 64-row block)
    int t2  = tloc2 + sh2;
    int n   = 128 + vb2 * 32 + l31;
    u16* dst = Vfrag + (size_t)bb * BSTRIDE +
               (size_t)((t2 * 4 + vb2) * 2 + thh) * 512 + l31 * 8;
#pragma unroll
    for (int hi = 0; hi < 2; ++hi) {
      U128 w;
#pragma unroll
      for (int j = 0; j < 8; ++j) {
        int s = sh2 * 32 + thh * 16 + hi * 8 + j;
        w.us[j] = Ct[s * 256 + (n ^ ((s & 7) << 3))];
      }
      *(uint4*)(dst + hi * 256) = w.u4;
    }
  }
}

// ---------------------------------------------------------------------------
// Kernel 2: causal flash attention (unchanged from R4 — verified passing).
// ---------------------------------------------------------------------------
__global__ void __launch_bounds__(256, 2) attn_kernel(
    const u16* __restrict__ Kfrag, const u16* __restrict__ Vfrag,
    float* __restrict__ out)
{
  __shared__ float Om[4][128][33];   // [slice][v][q] partial O^T
  __shared__ float Ml[4][2][32];     // [slice][m|l][q]
  __shared__ float Wm[4][32];        // merge weights
  __shared__ float Li[32];           // 1/L

  const int tid  = threadIdx.x;
  const int lane = tid & 63;
  const int w    = tid >> 6;         // KV slice 0..3
  const int l31  = lane & 31;
  const int hi   = lane >> 5;

  const int bi = blockIdx.x;
  const int b  = bi & 7;
  const int qt = (bi < 256) ? (63 - (bi >> 3)) : ((bi >> 3) - 32);
  const int q0 = qt * 32;

  const u16* Kb = Kfrag + (size_t)b * BSTRIDE;
  const u16* Vb = Vfrag + (size_t)b * BSTRIDE;
  const int loff = hi * 256 + l31 * 8;   // lane offset within a 512-u16 frag

  bf16x8 qf[8];
  {
    const u16* qp = Kb + (size_t)(qt * 8) * 512 + loff;
#pragma unroll
    for (int ks = 0; ks < 8; ++ks) {
      U128 u; u.u4 = *(const uint4*)(qp + ks * 512); qf[ks] = u.b8;
    }
  }

  f32x16 o[4];
#pragma unroll
  for (int vb2 = 0; vb2 < 4; ++vb2)
#pragma unroll
    for (int i = 0; i < 16; ++i) o[vb2][i] = 0.f;

  float mrun = -3.0e38f, lsum = 0.f;
  const float SC  = 0.08838834764831845f;   // 1/sqrt(128)
  const float L2E = 1.44269504088896341f;

  bf16x8 kf[8];
  {
    int ti0 = (w <= qt) ? w : 0;
    const u16* kp = Kb + (size_t)(ti0 * 8) * 512 + loff;
#pragma unroll
    for (int ks = 0; ks < 8; ++ks) {
      U128 u; u.u4 = *(const uint4*)(kp + ks * 512); kf[ks] = u.b8;
    }
  }

  for (int ti = w; ti <= qt; ti += 4) {
    bf16x8 vf[4][2];
    {
      const u16* vp = Vb + (size_t)(ti * 8) * 512 + loff;
#pragma unroll
      for (int vb2 = 0; vb2 < 4; ++vb2)
#pragma unroll
        for (int th = 0; th < 2; ++th) {
          U128 u; u.u4 = *(const uint4*)(vp + (vb2 * 2 + th) * 512);
          vf[vb2][th] = u.b8;
        }
    }
    f32x16 s;
#pragma unroll
    for (int i = 0; i < 16; ++i) s[i] = 0.f;
#pragma unroll
    for (int ks = 0; ks < 8; ++ks) s = mfma32(kf[ks], qf[ks], s);
    {
      int tin = (ti + 4 <= qt) ? ti + 4 : ti;
      const u16* kp = Kb + (size_t)(tin * 8) * 512 + loff;
#pragma unroll
      for (int ks = 0; ks < 8; ++ks) {
        U128 u; u.u4 = *(const uint4*)(kp + ks * 512); kf[ks] = u.b8;
      }
    }
    float sv[16];
#pragma unroll
    for (int r = 0; r < 16; ++r) sv[r] = s[r] * SC;
    if (ti == qt) {
#pragma unroll
      for (int r = 0; r < 16; ++r) {
        int toff = (r & 3) + 8 * (r >> 2) + 4 * hi;
        if (toff > l31) sv[r] = -3.0e38f;
      }
    }
    float mx = sv[0];
#pragma unroll
    for (int r = 1; r < 16; ++r) mx = fmaxf(mx, sv[r]);
    mx = fmaxf(mx, __shfl_xor(mx, 32));
    float p[16];
    float ps = 0.f;
    if (__all(mx - mrun <= 8.0f)) {
#pragma unroll
      for (int r = 0; r < 16; ++r) { p[r] = fexp2((sv[r] - mrun) * L2E); ps += p[r]; }
      ps += __shfl_xor(ps, 32);
      lsum += ps;
    } else {
      float mnew = fmaxf(mrun, mx);
      float al = fexp2((mrun - mnew) * L2E);
#pragma unroll
      for (int r = 0; r < 16; ++r) { p[r] = fexp2((sv[r] - mnew) * L2E); ps += p[r]; }
      ps += __shfl_xor(ps, 32);
      lsum = lsum * al + ps;
      mrun = mnew;
#pragma unroll
      for (int vb2 = 0; vb2 < 4; ++vb2)
#pragma unroll
        for (int i = 0; i < 16; ++i) o[vb2][i] *= al;
    }
    u32 c01 = (u32)f2bf(p[0])  | ((u32)f2bf(p[1])  << 16);
    u32 c23 = (u32)f2bf(p[2])  | ((u32)f2bf(p[3])  << 16);
    u32 c45 = (u32)f2bf(p[4])  | ((u32)f2bf(p[5])  << 16);
    u32 c67 = (u32)f2bf(p[6])  | ((u32)f2bf(p[7])  << 16);
    u32 c89 = (u32)f2bf(p[8])  | ((u32)f2bf(p[9])  << 16);
    u32 cAB = (u32)f2bf(p[10]) | ((u32)f2bf(p[11]) << 16);
    u32 cCD = (u32)f2bf(p[12]) | ((u32)f2bf(p[13]) << 16);
    u32 cEF = (u32)f2bf(p[14]) | ((u32)f2bf(p[15]) << 16);
    u32 d01 = __shfl_xor(c01, 32);
    u32 d23 = __shfl_xor(c23, 32);
    u32 d45 = __shfl_xor(c45, 32);
    u32 d67 = __shfl_xor(c67, 32);
    u32 d89 = __shfl_xor(c89, 32);
    u32 dAB = __shfl_xor(cAB, 32);
    u32 dCD = __shfl_xor(cCD, 32);
    u32 dEF = __shfl_xor(cEF, 32);
    U128 pf1, pf2;
    pf1.u[0] = hi ? d45 : c01;
    pf1.u[1] = hi ? d67 : c23;
    pf1.u[2] = hi ? c45 : d01;
    pf1.u[3] = hi ? c67 : d23;
    pf2.u[0] = hi ? dCD : c89;
    pf2.u[1] = hi ? dEF : cAB;
    pf2.u[2] = hi ? cCD : d89;
    pf2.u[3] = hi ? cEF : dAB;
#pragma unroll
    for (int vb2 = 0; vb2 < 4; ++vb2) {
      o[vb2] = mfma32(vf[vb2][0], pf1.b8, o[vb2]);
      o[vb2] = mfma32(vf[vb2][1], pf2.b8, o[vb2]);
    }
  }

#pragma unroll
  for (int vb2 = 0; vb2 < 4; ++vb2)
#pragma unroll
    for (int r = 0; r < 16; ++r) {
      int v = vb2 * 32 + (r & 3) + 8 * (r >> 2) + 4 * hi;
      Om[w][v][l31] = o[vb2][r];
    }
  if (lane < 32) {
    Ml[w][0][l31] = mrun;
    Ml[w][1][l31] = lsum;
  }
  __syncthreads();

  if (tid < 32) {
    float m0 = Ml[0][0][tid], m1 = Ml[1][0][tid];
    float m2 = Ml[2][0][tid], m3 = Ml[3][0][tid];
    float M  = fmaxf(fmaxf(m0, m1), fmaxf(m2, m3));
    float w0 = fexp2((m0 - M) * L2E), w1 = fexp2((m1 - M) * L2E);
    float w2 = fexp2((m2 - M) * L2E), w3 = fexp2((m3 - M) * L2E);
    float L  = Ml[0][1][tid] * w0 + Ml[1][1][tid] * w1 +
               Ml[2][1][tid] * w2 + Ml[3][1][tid] * w3;
    Wm[0][tid] = w0; Wm[1][tid] = w1; Wm[2][tid] = w2; Wm[3][tid] = w3;
    Li[tid] = 1.f / L;
  }
  __syncthreads();

  {
    const int q = tid >> 3;
    const int vbase = (tid & 7) * 16;
    float wq0 = Wm[0][q], wq1 = Wm[1][q], wq2 = Wm[2][q], wq3 = Wm[3][q];
    float li = Li[q];
    float* orow = out + (size_t)(b * SEQ + q0 + q) * OD + 1024 + vbase;
#pragma unroll
    for (int i = 0; i < 16; i += 4) {
      float4 res;
      res.x = (Om[0][vbase + i + 0][q] * wq0 + Om[1][vbase + i + 0][q] * wq1 +
               Om[2][vbase + i + 0][q] * wq2 + Om[3][vbase + i + 0][q] * wq3) * li;
      res.y = (Om[0][vbase + i + 1][q] * wq0 + Om[1][vbase + i + 1][q] * wq1 +
               Om[2][vbase + i + 1][q] * wq2 + Om[3][vbase + i + 1][q] * wq3) * li;
      res.z = (Om[0][vbase + i + 2][q] * wq0 + Om[1][vbase + i + 2][q] * wq1 +
               Om[2][vbase + i + 2][q] * wq2 + Om[3][vbase + i + 2][q] * wq3) * li;
      res.w = (Om[0][vbase + i + 3][q] * wq0 + Om[1][vbase + i + 3][q] * wq1 +
               Om[2][vbase + i + 3][q] * wq2 + Om[3][vbase + i + 3][q] * wq3) * li;
      *(float4*)(orow + i) = res;
    }
  }
}

extern "C" void kernel_launch(void* const* d_in, const int* in_sizes, int n_in,
                              void* d_out, int out_size, void* d_ws, size_t ws_size,
                              hipStream_t stream)
{
  const float* X  = (const float*)d_in[0];
  const float* Wk = (const float*)d_in[1];
  const float* bk = (const float*)d_in[2];
  const float* Wv = (const float*)d_in[3];
  const float* bv = (const float*)d_in[4];
  float* out = (float*)d_out;

  u16* Kfrag  = (u16*)d_ws;                                // 4 MB
  u16* Vfrag  = Kfrag + (size_t)BATCH * BSTRIDE;           // 4 MB
  u16* Wtiles = Vfrag + (size_t)BATCH * BSTRIDE;           // 512 KB

  prep_kernel<<<dim3(128), dim3(256), 0, stream>>>(Wk, Wv, Wtiles);
  proj_kernel<<<dim3(256), dim3(512), 0, stream>>>(X, Wtiles, bk, bv, out, Kfrag, Vfrag);
  attn_kernel<<<dim3(512), dim3(256), 0, stream>>>(Kfrag, Vfrag, out);
}